// Round 1
// baseline (118.124 us; speedup 1.0000x reference)
//
#include <hip/hip_runtime.h>
#include <hip/hip_bf16.h>
#include <stdint.h>

#define BTOT 4096
#define RR   64
#define DIMD 128
#define NB   8
#define NBLK (BTOT / NB)   /* 512 blocks */

typedef short s16x8 __attribute__((ext_vector_type(8)));
typedef float f32x4 __attribute__((ext_vector_type(4)));

__device__ __forceinline__ unsigned short f2bf(float x) {
  __hip_bfloat16 h = __float2bfloat16(x);
  return __builtin_bit_cast(unsigned short, h);
}
__device__ __forceinline__ float bf2f(unsigned short u) {
  unsigned int v = ((unsigned int)u) << 16;
  return __builtin_bit_cast(float, v);
}

// ---------------------------------------------------------------------------
// Pre-kernel: qproj[b,k] = sum_d query_r[b,d]*W1[k,128+d] + b1[k]  (fp32)
// plus blocks 0/1 emit XOR-swizzled bf16 copies of W1a and W2 into ws.
// Swizzle convention: element (k,d) stored at  k*128 + (d ^ ((k&7)<<3)).
// ---------------------------------------------------------------------------
__global__ __launch_bounds__(256) void prep_kernel(
    const float* __restrict__ W1, const float* __restrict__ b1,
    const float* __restrict__ query_r, const float* __restrict__ W2,
    float* __restrict__ qproj, unsigned short* __restrict__ w1a_swz,
    unsigned short* __restrict__ w2_swz)
{
  __shared__ float w1b[128 * 132];   // +4 pad: even bank spread for b128 reads
  __shared__ float qrs[256];
  const int tid = threadIdx.x;

  { // stage W1b fp32 into padded LDS (thread t: row t>>1, 64 elems)
    const int k = tid >> 1, d0 = (tid & 1) * 64;
    const float* src = W1 + k * 256 + 128 + d0;
    float* dst = &w1b[k * 132 + d0];
    #pragma unroll
    for (int i = 0; i < 64; i += 4)
      *reinterpret_cast<float4*>(dst + i) = *reinterpret_cast<const float4*>(src + i);
  }
  if (blockIdx.x < 2) { // swizzled bf16 weights
    const float* Wsrc = (blockIdx.x == 0) ? W1 : W2;
    unsigned short* dstw = (blockIdx.x == 0) ? w1a_swz : w2_swz;
    const int stride = (blockIdx.x == 0) ? 256 : 128;
    for (int i = tid; i < 128 * 128; i += 256) {
      const int k = i >> 7, d = i & 127;
      dstw[k * 128 + (d ^ ((k & 7) << 3))] = f2bf(Wsrc[k * stride + d]);
    }
  }
  __syncthreads();

  const int b0 = blockIdx.x * NB;
  const int k = tid & 127, bh = tid >> 7;
  for (int p = 0; p < NB / 2; ++p) {
    const int b = b0 + p * 2;
    qrs[tid] = query_r[(size_t)(b + bh) * DIMD + k];
    __syncthreads();
    float acc = b1[k];
    const float* qq = &qrs[bh * 128];
    const float* wr = &w1b[k * 132];
    #pragma unroll
    for (int d = 0; d < 128; d += 4) {
      float4 wv = *reinterpret_cast<const float4*>(wr + d);
      float4 qv = *reinterpret_cast<const float4*>(qq + d);
      acc = fmaf(wv.x, qv.x, acc); acc = fmaf(wv.y, qv.y, acc);
      acc = fmaf(wv.z, qv.z, acc); acc = fmaf(wv.w, qv.w, acc);
    }
    qproj[(size_t)(b + bh) * DIMD + k] = acc;
    __syncthreads();
  }
}

// ---------------------------------------------------------------------------
// Main kernel: per block 8 b's. LDS = W1a(32K) + W2(32K) + per-wave 4K = 80K
// -> 2 blocks/CU. Each wave owns rows [16w,16w+16): staging, h-transpose and
// GEMM rows are wave-private (no barriers except the partial-sum exchange).
// MFMA 16x16x32 bf16: A/B frag = row (l&15), k = 8*(l>>4)+j (8 contiguous);
// C/D: col = l&15, row = 4*(l>>4)+reg  [learn_hip m89/m92 verified].
// ---------------------------------------------------------------------------
__global__ __launch_bounds__(256, 2) void main_kernel(
    const float* __restrict__ query_emb, const float* __restrict__ offset_emb,
    const float* __restrict__ refer_embs, const float* __restrict__ refer_r,
    const float* __restrict__ start_embs, const float* __restrict__ b2,
    const float* __restrict__ qproj, const unsigned short* __restrict__ w1a_swz,
    const unsigned short* __restrict__ w2_swz, float* __restrict__ out)
{
  __shared__ unsigned short lds_w1a[128 * 128];
  __shared__ unsigned short lds_w2[128 * 128];
  __shared__ unsigned short lds_rr[4][16 * 128];   // per-wave refer_r / h / partials

  const int tid  = threadIdx.x;
  const int wave = tid >> 6;
  const int lane = tid & 63;
  const int g    = lane >> 4;   // k-group
  const int c    = lane & 15;   // row/col-in-tile

  { // stage swizzled weights (linear copy; swizzle already applied in ws)
    const uint4* s1 = reinterpret_cast<const uint4*>(w1a_swz);
    const uint4* s2 = reinterpret_cast<const uint4*>(w2_swz);
    uint4* d1 = reinterpret_cast<uint4*>(lds_w1a);
    uint4* d2 = reinterpret_cast<uint4*>(lds_w2);
    #pragma unroll
    for (int i = 0; i < 8; ++i) {
      d1[tid + 256 * i] = s1[tid + 256 * i];
      d2[tid + 256 * i] = s2[tid + 256 * i];
    }
  }
  __syncthreads();

  unsigned short* myrr = &lds_rr[wave][0];
  const int srl = lane >> 2;           // staging: local row 0..15
  const int sd0 = (lane & 3) * 32;     // staging: 32 floats per lane
  const int rl4 = 4 * g;               // C-position base local row

  for (int bb = 0; bb < NB; ++bb) {
    const int b = blockIdx.x * NB + bb;
    const size_t base = (size_t)b * RR * DIMD;

    // ---- issue refer_r staging loads (wave-private rows)
    const float* rp = refer_r + base + (size_t)(wave * 16 + srl) * DIMD + sd0;
    float4 fv[8];
    #pragma unroll
    for (int i = 0; i < 8; ++i) fv[i] = *reinterpret_cast<const float4*>(rp + 4 * i);

    // ---- issue bias loads early (immediate-offset scalar loads)
    const float* pre = refer_embs + base + (size_t)(wave * 16 + rl4) * DIMD + c;
    const float* pse = start_embs + base + (size_t)(wave * 16 + rl4) * DIMD + c;
    float rebv[32], sebv[32];
    #pragma unroll
    for (int nt = 0; nt < 8; ++nt)
      #pragma unroll
      for (int r = 0; r < 4; ++r) {
        rebv[nt * 4 + r] = pre[r * DIMD + nt * 16];
        sebv[nt * 4 + r] = pse[r * DIMD + nt * 16];
      }

    __syncthreads();  // protect LDS partials of previous iter from overwrite

    // ---- stage refer_r -> LDS bf16, swizzled
    {
      const int sw_s = (srl & 7) << 3;
      unsigned short* wrow = &myrr[srl * DIMD];
      #pragma unroll
      for (int gi = 0; gi < 4; ++gi) {
        union { unsigned short u[8]; uint4 v; } pk;
        const float4 a = fv[2 * gi], bq = fv[2 * gi + 1];
        pk.u[0] = f2bf(a.x);  pk.u[1] = f2bf(a.y);
        pk.u[2] = f2bf(a.z);  pk.u[3] = f2bf(a.w);
        pk.u[4] = f2bf(bq.x); pk.u[5] = f2bf(bq.y);
        pk.u[6] = f2bf(bq.z); pk.u[7] = f2bf(bq.w);
        *reinterpret_cast<uint4*>(&wrow[(sd0 + gi * 8) ^ sw_s]) = pk.v;
      }
    }
    asm volatile("s_waitcnt lgkmcnt(0)" ::: "memory");  // cross-lane via LDS

    // ---- refer_r at C-positions (bias term) + A-frags
    float rrv[32];
    #pragma unroll
    for (int nt = 0; nt < 8; ++nt)
      #pragma unroll
      for (int r = 0; r < 4; ++r) {
        const int rl = rl4 + r;
        const int d = nt * 16 + c;
        rrv[nt * 4 + r] = bf2f(myrr[rl * DIMD + (d ^ ((rl & 7) << 3))]);
      }
    s16x8 af[4];
    {
      const int sw = (c & 7) << 3;
      #pragma unroll
      for (int ks = 0; ks < 4; ++ks)
        af[ks] = *reinterpret_cast<const s16x8*>(&myrr[c * DIMD + ((ks * 32 + g * 8) ^ sw)]);
    }

    // ---- GEMM1: h = refer_r * W1a^T (+ qproj incl. b1)
    f32x4 Ch[8];
    #pragma unroll
    for (int nt = 0; nt < 8; ++nt) {
      const float qv = qproj[(size_t)b * DIMD + nt * 16 + c];
      Ch[nt] = (f32x4){qv, qv, qv, qv};
    }
    #pragma unroll
    for (int ks = 0; ks < 4; ++ks)
      #pragma unroll
      for (int nt = 0; nt < 8; ++nt) {
        const int kr = nt * 16 + c;
        s16x8 bf = *reinterpret_cast<const s16x8*>(
            &lds_w1a[kr * DIMD + ((ks * 32 + g * 8) ^ ((kr & 7) << 3))]);
        Ch[nt] = __builtin_amdgcn_mfma_f32_16x16x32_bf16(af[ks], bf, Ch[nt], 0, 0, 0);
      }

    // ---- bias combine (frees rebv/sebv)
    float biasv[32];
    #pragma unroll
    for (int i = 0; i < 32; ++i) biasv[i] = rebv[i] - sebv[i] - rrv[i];

    // ---- h (relu, bf16) overwrites wave's LDS slice
    asm volatile("s_waitcnt lgkmcnt(0)" ::: "memory");  // rr reads done
    #pragma unroll
    for (int nt = 0; nt < 8; ++nt)
      #pragma unroll
      for (int r = 0; r < 4; ++r) {
        const int rl = rl4 + r;
        const int d = nt * 16 + c;
        myrr[rl * DIMD + (d ^ ((rl & 7) << 3))] = f2bf(fmaxf(Ch[nt][r], 0.f));
      }
    asm volatile("s_waitcnt lgkmcnt(0)" ::: "memory");  // h visible to wave

    // ---- GEMM2: attn = h * W2^T (+ b2)
    s16x8 hf[4];
    {
      const int sw = (c & 7) << 3;
      #pragma unroll
      for (int ks = 0; ks < 4; ++ks)
        hf[ks] = *reinterpret_cast<const s16x8*>(&myrr[c * DIMD + ((ks * 32 + g * 8) ^ sw)]);
    }
    f32x4 Ca[8];
    #pragma unroll
    for (int nt = 0; nt < 8; ++nt) {
      const float bv = b2[nt * 16 + c];
      Ca[nt] = (f32x4){bv, bv, bv, bv};
    }
    #pragma unroll
    for (int ks = 0; ks < 4; ++ks)
      #pragma unroll
      for (int nt = 0; nt < 8; ++nt) {
        const int dr = nt * 16 + c;
        s16x8 wf = *reinterpret_cast<const s16x8*>(
            &lds_w2[dr * DIMD + ((ks * 32 + g * 8) ^ ((dr & 7) << 3))]);
        Ca[nt] = __builtin_amdgcn_mfma_f32_16x16x32_bf16(hf[ks], wf, Ca[nt], 0, 0, 0);
      }

    // ---- psum over wave rows, then block reduce via LDS
    float psum[8];
    #pragma unroll
    for (int nt = 0; nt < 8; ++nt) {
      float s = 0.f;
      #pragma unroll
      for (int r = 0; r < 4; ++r) s = fmaf(Ca[nt][r], biasv[nt * 4 + r], s);
      s += __shfl_xor(s, 16);
      s += __shfl_xor(s, 32);
      psum[nt] = s;
    }
    float* pp = reinterpret_cast<float*>(&lds_rr[0][0]);  // 512 f32 scratch
    __syncthreads();
    if (lane < 16) {
      #pragma unroll
      for (int nt = 0; nt < 8; ++nt) pp[wave * 128 + nt * 16 + c] = psum[nt];
    }
    __syncthreads();
    if (tid < 128) {
      const float s = pp[tid] + pp[tid + 128] + pp[tid + 256] + pp[tid + 384];
      out[(size_t)b * DIMD + tid] = query_emb[(size_t)b * DIMD + tid] + s;
    }
  }

  // ---- offset_emb passthrough (second output)
  {
    const size_t ob = (size_t)blockIdx.x * NB * DIMD;
    #pragma unroll
    for (int i = 0; i < (NB * DIMD) / 256; ++i) {
      const size_t idx = ob + tid + 256 * i;
      out[(size_t)BTOT * DIMD + idx] = offset_emb[idx];
    }
  }
}

extern "C" void kernel_launch(void* const* d_in, const int* in_sizes, int n_in,
                              void* d_out, int out_size, void* d_ws, size_t ws_size,
                              hipStream_t stream) {
  const float* query_emb  = (const float*)d_in[0];
  const float* offset_emb = (const float*)d_in[1];
  const float* refer_embs = (const float*)d_in[2];
  const float* query_r    = (const float*)d_in[3];
  const float* refer_r    = (const float*)d_in[4];
  const float* start_embs = (const float*)d_in[5];
  const float* W1 = (const float*)d_in[6];
  const float* b1 = (const float*)d_in[7];
  const float* W2 = (const float*)d_in[8];
  const float* b2 = (const float*)d_in[9];
  float* out = (float*)d_out;

  float* qproj = (float*)d_ws;                       // 4096*128 f32 = 2 MB
  unsigned short* w1a_swz =
      (unsigned short*)((char*)d_ws + (size_t)BTOT * DIMD * sizeof(float));
  unsigned short* w2_swz = w1a_swz + 128 * 128;      // +32 KB each

  hipLaunchKernelGGL(prep_kernel, dim3(NBLK), dim3(256), 0, stream,
                     W1, b1, query_r, W2, qproj, w1a_swz, w2_swz);
  hipLaunchKernelGGL(main_kernel, dim3(NBLK), dim3(256), 0, stream,
                     query_emb, offset_emb, refer_embs, refer_r, start_embs,
                     b2, qproj, w1a_swz, w2_swz, out);
}